// Round 16
// baseline (577.682 us; speedup 1.0000x reference)
//
#include <hip/hip_runtime.h>
#include <hip/hip_bf16.h>
#include <math.h>

#define DI __device__ __forceinline__

typedef unsigned short u16;
typedef unsigned int   u32;
typedef unsigned long long u64;
typedef __attribute__((ext_vector_type(8))) short short8;   // 8 bf16 (4 VGPRs) MFMA A/B frag
typedef __attribute__((ext_vector_type(4))) float f32x4;    // MFMA C/D frag

constexpr int CB = 512;    // channels
constexpr int LL = 4096;   // length
constexpr int NG = 32;     // groups
constexpr long NELC = (long)LL * CB;       // elems per [l][c] plane

DI float bf2f(u16 u) { u32 v = ((u32)u) << 16; float f; __builtin_memcpy(&f, &v, 4); return f; }
DI u16 f2bf(float f) {
  u32 u; __builtin_memcpy(&u, &f, 4);
  u += 0x7fffu + ((u >> 16) & 1u);   // RNE
  return (u16)(u >> 16);
}

DI void gload16(const void* g, void* l) {
  __builtin_amdgcn_global_load_lds((const __attribute__((address_space(1))) u32*)g,
                                   (__attribute__((address_space(3))) u32*)l, 16, 0, 0);
}

// ---------------------------------------------------------------------------
// K0: prep = conv_w (weights->bf16, fused bias) UNION gn_stats (one dispatch).
// ---------------------------------------------------------------------------
__global__ __launch_bounds__(256) void prep(
    const float* __restrict__ wq, const float* __restrict__ wk,
    const float* __restrict__ wv, const float* __restrict__ wo,
    const float* __restrict__ bq, const float* __restrict__ bk,
    const float* __restrict__ bv, const float* __restrict__ x,
    u16* __restrict__ wqkv, u16* __restrict__ wob, float* __restrict__ bqkv,
    float* __restrict__ stats) {
  if (blockIdx.x < 1024) {
    int i = blockIdx.x * 256 + threadIdx.x;
    wqkv[i]          = f2bf(wq[i]);
    wqkv[262144 + i] = f2bf(wk[i]);
    wqkv[524288 + i] = f2bf(wv[i]);
    wob[i]           = f2bf(wo[i]);
  } else if (blockIdx.x == 1024) {
    for (int j = 0; j < 6; ++j) {
      int idx = j * 256 + threadIdx.x;
      float b = (idx < 512) ? bq[idx] : (idx < 1024) ? bk[idx - 512] : bv[idx - 1024];
      bqkv[idx] = b;
    }
  } else {
    const int bid = blockIdx.x - 1025;            // 0..255 = (b,g)
    const float4* base = (const float4*)(x + (long)bid * (16 * LL));
    float s = 0.f, ss = 0.f;
    for (int i = threadIdx.x; i < 16 * LL / 4; i += 256) {
      float4 v = base[i];
      s  += v.x + v.y + v.z + v.w;
      ss += v.x * v.x + v.y * v.y + v.z * v.z + v.w * v.w;
    }
#pragma unroll
    for (int o = 32; o; o >>= 1) { s += __shfl_xor(s, o); ss += __shfl_xor(ss, o); }
    __shared__ float red[8];
    int wv2 = threadIdx.x >> 6, ln = threadIdx.x & 63;
    if (ln == 0) { red[wv2 * 2] = s; red[wv2 * 2 + 1] = ss; }
    __syncthreads();
    if (threadIdx.x == 0) {
      float S = red[0] + red[2] + red[4] + red[6];
      float SS = red[1] + red[3] + red[5] + red[7];
      float mu = S * (1.f / 65536.f);
      float var = SS * (1.f / 65536.f) - mu * mu;
      stats[bid * 2]     = mu;
      stats[bid * 2 + 1] = rsqrtf(var + 1e-6f);
    }
  }
}

// ---------------------------------------------------------------------------
// K2: GroupNorm apply + transpose (vectorized): hT[b][l][c] = bf16(gn(x))
// ---------------------------------------------------------------------------
__global__ __launch_bounds__(256) void gn_apply(
    const float* __restrict__ x, const float* __restrict__ gw,
    const float* __restrict__ gb, const float* __restrict__ stats,
    u16* __restrict__ hT) {
  __shared__ u16 t[64][66];                      // [c][l] padded tile
  const int b = blockIdx.z, c0 = blockIdx.y * 64, l0 = blockIdx.x * 64;
  const int tid = threadIdx.x;
#pragma unroll
  for (int p = 0; p < 4; ++p) {
    const int cr = p * 16 + (tid >> 4);
    const int lq = (tid & 15) * 4;
    const int c = c0 + cr;
    const float mu = stats[(b * NG + (c >> 4)) * 2];
    const float rs = stats[(b * NG + (c >> 4)) * 2 + 1];
    const float g = gw[c], be = gb[c];
    float4 v = *(const float4*)(x + (long)b * CB * LL + (long)c * LL + l0 + lq);
    t[cr][lq + 0] = f2bf((v.x - mu) * rs * g + be);
    t[cr][lq + 1] = f2bf((v.y - mu) * rs * g + be);
    t[cr][lq + 2] = f2bf((v.z - mu) * rs * g + be);
    t[cr][lq + 3] = f2bf((v.w - mu) * rs * g + be);
  }
  __syncthreads();
#pragma unroll
  for (int it = 0; it < 2; ++it) {
    const int i = it * 2048 + tid * 8;           // element id within 64x64
    const int lr = i >> 6, cc = i & 63;
    short8 val;
#pragma unroll
    for (int j = 0; j < 8; ++j) val[j] = (short)t[cc + j][lr];
    *(short8*)(hT + (long)b * LL * CB + (long)(l0 + lr) * CB + c0 + cc) = val;
  }
}

// ---------------------------------------------------------------------------
// 8-phase 256x256 GEMM (HK schedule, plain HIP): D = A[M][K] * Bt[N][K]^T.
// (proven r10-r15 engine; see comments in r10)
// EPI: 0 = QKV   1 = expS (+register-neutral store-loop row sums -> spp)
// ---------------------------------------------------------------------------
template <int Q>
DI void rdA(const u16* LB, int wr, int fr, int fq, short8 af[2][2]) {
#pragma unroll
  for (int m2 = 0; m2 < 2; ++m2)
#pragma unroll
    for (int kk = 0; kk < 2; ++kk) {
      const int R = wr * 128 + (Q * 2 + m2) * 16 + fr;
      af[m2][kk] = *(const short8*)((const char*)LB + R * 128 +
                                    ((kk * 64 + fq * 16) ^ ((R & 7) << 4)));
    }
}
DI void rdB(const u16* LB, int wc, int fr, int fq, short8 bf[4][2]) {
#pragma unroll
  for (int nf = 0; nf < 4; ++nf)
#pragma unroll
    for (int kk = 0; kk < 2; ++kk) {
      const int R = wc * 64 + nf * 16 + fr;
      bf[nf][kk] = *(const short8*)((const char*)LB + R * 128 +
                                    ((kk * 64 + fq * 16) ^ ((R & 7) << 4)));
    }
}
template <int Q>
DI void mmaQ(short8 af[2][2], short8 bf[4][2], f32x4 acc[8][4]) {
#pragma unroll
  for (int kk = 0; kk < 2; ++kk)
#pragma unroll
    for (int m2 = 0; m2 < 2; ++m2)
#pragma unroll
      for (int nf = 0; nf < 4; ++nf)
        acc[Q * 2 + m2][nf] = __builtin_amdgcn_mfma_f32_16x16x32_bf16(
            af[m2][kk], bf[nf][kk], acc[Q * 2 + m2][nf], 0, 0, 0);
}

#define PTAIL(Q)                                             \
  __builtin_amdgcn_s_barrier();                              \
  asm volatile("s_waitcnt lgkmcnt(0)" ::: "memory");         \
  __builtin_amdgcn_sched_barrier(0);                         \
  __builtin_amdgcn_s_setprio(1);                             \
  mmaQ<Q>(af, bf, acc);                                      \
  __builtin_amdgcn_s_setprio(0);                             \
  __builtin_amdgcn_s_barrier();

template <int EPI>
__global__ __launch_bounds__(512, 2) void gemm8p(
    const u16* __restrict__ A, int lda, long asb,
    const u16* __restrict__ Bt, int ldb, long bsb,
    int K, const float* __restrict__ bias, float scale,
    u16* __restrict__ o0, u16* __restrict__ o1, u16* __restrict__ o2,
    float* __restrict__ spp, long osb, int ldo) {
  __shared__ u16 smem[65536];                  // 128 KB
  u16* lA0 = smem;
  u16* lA1 = smem + 16384;
  u16* lB0 = smem + 32768;
  u16* lB1 = smem + 49152;

  const int tid = threadIdx.x;
  const int lane = tid & 63, wv = tid >> 6;
  const int wr = wv >> 2, wc = wv & 3;         // 2 x 4 waves
  const int fr = lane & 15, fq = lane >> 4;
  const int bx = blockIdx.x, by = blockIdx.y, bz = blockIdx.z;

  const u16* Ab = A + (long)bz * asb + (long)(by * 256) * lda;
  const u16* Bb = Bt + (long)bz * bsb + (long)(bx * 256) * ldb;

  auto stage = [&](u16* lbase, const u16* gbase, int ld_, int half, int t) {
#pragma unroll
    for (int p = 0; p < 2; ++p) {
      int i = p * 512 + tid;
      int row = i >> 3, ch = i & 7;
      int src = t * 64 + ((((ch << 4) ^ ((row & 7) << 4))) >> 1);
      gload16(gbase + (long)(half * 128 + row) * ld_ + src,
              lbase + half * 8192 + i * 8);
    }
  };

  f32x4 acc[8][4];
#pragma unroll
  for (int m = 0; m < 8; ++m)
#pragma unroll
    for (int n = 0; n < 4; ++n) acc[m][n] = (f32x4)(0.f);

  stage(lA0, Ab, lda, 0, 0); stage(lA0, Ab, lda, 1, 0);
  stage(lB0, Bb, ldb, 0, 0); stage(lB0, Bb, ldb, 1, 0);
  stage(lB1, Bb, ldb, 0, 1); stage(lB1, Bb, ldb, 1, 1);
  asm volatile("s_waitcnt vmcnt(4)" ::: "memory");
  __builtin_amdgcn_sched_barrier(0);
  __builtin_amdgcn_s_barrier();

  const int nt = K >> 6;
  short8 af[2][2], bf[4][2];
  for (int i = 0; i < nt / 2; ++i) {
    const bool last = (i == nt / 2 - 1);
    const int t1 = 2 * i + 1, t2 = 2 * i + 2, t3 = 2 * i + 3;
    rdB(lB0, wc, fr, fq, bf);
    rdA<0>(lA0, wr, fr, fq, af);
    stage(lA1, Ab, lda, 0, t1);
    PTAIL(0)
    rdA<1>(lA0, wr, fr, fq, af);
    stage(lA1, Ab, lda, 1, t1);
    PTAIL(1)
    rdA<2>(lA0, wr, fr, fq, af);
    if (!last) stage(lB0, Bb, ldb, 0, t2);
    PTAIL(2)
    rdA<3>(lA0, wr, fr, fq, af);
    if (!last) stage(lB0, Bb, ldb, 1, t2);
    if (last) { asm volatile("s_waitcnt vmcnt(0)" ::: "memory"); }
    else      { asm volatile("s_waitcnt vmcnt(4)" ::: "memory"); }
    __builtin_amdgcn_sched_barrier(0);
    PTAIL(3)
    rdB(lB1, wc, fr, fq, bf);
    rdA<0>(lA1, wr, fr, fq, af);
    if (!last) stage(lA0, Ab, lda, 0, t2);
    PTAIL(0)
    rdA<1>(lA1, wr, fr, fq, af);
    if (!last) stage(lA0, Ab, lda, 1, t2);
    PTAIL(1)
    rdA<2>(lA1, wr, fr, fq, af);
    if (!last) stage(lB1, Bb, ldb, 0, t3);
    PTAIL(2)
    rdA<3>(lA1, wr, fr, fq, af);
    if (!last) stage(lB1, Bb, ldb, 1, t3);
    if (!last) {
      asm volatile("s_waitcnt vmcnt(4)" ::: "memory");
      __builtin_amdgcn_sched_barrier(0);
    }
    PTAIL(3)
  }

  if constexpr (EPI == 1) {
    // expS: bf16(exp2(acc*scale)) + register-neutral store-loop row sums
#pragma unroll
    for (int mf = 0; mf < 8; ++mf)
#pragma unroll
      for (int nf = 0; nf < 4; ++nf) {
        const int nl = wc * 64 + nf * 16 + fr;
#pragma unroll
        for (int r = 0; r < 4; ++r) {
          const int ml = wr * 128 + mf * 16 + fq * 4 + r;
          smem[ml * 256 + (nl ^ ((ml & 7) << 3))] =
              f2bf(exp2f(acc[mf][nf][r] * scale));
        }
      }
    __syncthreads();
    u16* dst0 = o0 + (long)bz * osb + (long)(by * 256) * ldo + bx * 256;
    float* sppb = spp + ((long)bz * 16 + bx) * LL + by * 256;
    for (int i = tid * 8; i < 65536; i += 4096) {
      const int rr = i >> 8, cc = i & 255;
      short8 val = *(const short8*)&smem[rr * 256 + (cc ^ ((rr & 7) << 3))];
      *(short8*)(dst0 + (long)rr * ldo + cc) = val;
      float s = 0.f;
#pragma unroll
      for (int j = 0; j < 8; ++j) s += bf2f((u16)val[j]);
      s += __shfl_xor(s, 1);  s += __shfl_xor(s, 2);
      s += __shfl_xor(s, 4);  s += __shfl_xor(s, 8);
      s += __shfl_xor(s, 16);
      if ((tid & 31) == 0) sppb[rr] = s;
    }
  } else {
    // QKV: by 0,1 -> q; 2,3 -> k (transposed [l][c]); 4,5 -> v (natural [c][l])
    const int mat = by >> 1;
    if (mat < 2) {
#pragma unroll
      for (int mf = 0; mf < 8; ++mf)
#pragma unroll
        for (int nf = 0; nf < 4; ++nf) {
          const int nl = wc * 64 + nf * 16 + fr;
#pragma unroll
          for (int r = 0; r < 4; ++r) {
            const int ml = wr * 128 + mf * 16 + fq * 4 + r;
            smem[nl * 256 + (ml ^ ((nl & 7) << 3))] =
                f2bf(acc[mf][nf][r] + bias[by * 256 + ml]);
          }
        }
      __syncthreads();
      u16* dst0 = (mat == 0 ? o0 : o1) + (long)bz * NELC +
                  (long)(bx * 256) * CB + ((by * 256) & 511);
      for (int i = tid * 8; i < 65536; i += 4096) {
        const int rr = i >> 8, cc = i & 255;
        short8 val = *(const short8*)&smem[rr * 256 + (cc ^ ((rr & 7) << 3))];
        *(short8*)(dst0 + (long)rr * CB + cc) = val;
      }
    } else {
#pragma unroll
      for (int mf = 0; mf < 8; ++mf)
#pragma unroll
        for (int nf = 0; nf < 4; ++nf) {
          const int nl = wc * 64 + nf * 16 + fr;
#pragma unroll
          for (int r = 0; r < 4; ++r) {
            const int ml = wr * 128 + mf * 16 + fq * 4 + r;
            smem[ml * 256 + (nl ^ ((ml & 7) << 3))] =
                f2bf(acc[mf][nf][r] + bias[by * 256 + ml]);
          }
        }
      __syncthreads();
      u16* dst0 = o2 + (long)bz * ((long)CB * LL) +
                  (long)((by * 256) & 511) * LL + bx * 256;
      for (int i = tid * 8; i < 65536; i += 4096) {
        const int rr = i >> 8, cc = i & 255;
        short8 val = *(const short8*)&smem[rr * 256 + (cc ^ ((rr & 7) << 3))];
        *(short8*)(dst0 + (long)rr * LL + cc) = val;
      }
    }
  }
}

// ---------------------------------------------------------------------------
// gemm8pw: wide-B 8-phase PV.  D = A[M][K]*Bt[N][K]^T with BM=128, BN=512;
// each S row staged ONCE per dispatch (r15 diagnosis: PV's cold 2x S re-read).
// Mirror of gemm8p's schedule with A/B roles swapped:
//   frags: A (4 m-frags) hoisted to phase 1; B 2 n-frags per phase (Q = n-quad).
//   stages: ph1,2 -> lB1(t1); ph3,4 -> lA0(t2); ph5,6 -> lB0(t2); ph7,8 -> lA1(t3)
//   A-half = 1 gload/thr, B-half = 4 gloads/thr -> counted wait = vmcnt(2)
//   (leaves newest A-stage pair), vmcnt(0) at last ph4.  LDS 160 KB.
// blockIdx: x = by (m-tile 0..31), z = batchInPair*4 + chunk; K = 1024.
// Epilogue: rls computed in-kernel from spp (post-loop, register-neutral);
// bf16(acc*rl[row]) -> per-batch [4096][2048] chunk-interleaved partials.
// ---------------------------------------------------------------------------
DI void rdAall(const u16* LB, int wr, int fr, int fq, short8 af[4][2]) {
#pragma unroll
  for (int mf = 0; mf < 4; ++mf)
#pragma unroll
    for (int kk = 0; kk < 2; ++kk) {
      const int R = wr * 64 + mf * 16 + fr;
      af[mf][kk] = *(const short8*)((const char*)LB + R * 128 +
                                    ((kk * 64 + fq * 16) ^ ((R & 7) << 4)));
    }
}
template <int Q>
DI void rdB2(const u16* LB, int wc, int fr, int fq, short8 bq[2][2]) {
#pragma unroll
  for (int n2 = 0; n2 < 2; ++n2)
#pragma unroll
    for (int kk = 0; kk < 2; ++kk) {
      const int R = wc * 128 + (Q * 2 + n2) * 16 + fr;
      bq[n2][kk] = *(const short8*)((const char*)LB + R * 128 +
                                    ((kk * 64 + fq * 16) ^ ((R & 7) << 4)));
    }
}
template <int Q>
DI void mmaQ2(short8 af[4][2], short8 bq[2][2], f32x4 acc[4][8]) {
#pragma unroll
  for (int kk = 0; kk < 2; ++kk)
#pragma unroll
    for (int mf = 0; mf < 4; ++mf)
#pragma unroll
      for (int n2 = 0; n2 < 2; ++n2)
        acc[mf][Q * 2 + n2] = __builtin_amdgcn_mfma_f32_16x16x32_bf16(
            af[mf][kk], bq[n2][kk], acc[mf][Q * 2 + n2], 0, 0, 0);
}

#define PTAILW(Q)                                            \
  __builtin_amdgcn_s_barrier();                              \
  asm volatile("s_waitcnt lgkmcnt(0)" ::: "memory");         \
  __builtin_amdgcn_sched_barrier(0);                         \
  __builtin_amdgcn_s_setprio(1);                             \
  mmaQ2<Q>(af, bq, acc);                                     \
  __builtin_amdgcn_s_setprio(0);                             \
  __builtin_amdgcn_s_barrier();

__global__ __launch_bounds__(512, 2) void gemm8pw(
    const u16* __restrict__ A, int lda, long asb,
    const u16* __restrict__ Bt, int ldb, long bsb,
    int K, u16* __restrict__ o0, const float* __restrict__ spp, int ldo) {
  __shared__ u16 smem[81920];                  // 160 KB
  u16* lA0 = smem;                             // [128][64] = 16 KB
  u16* lA1 = smem + 8192;
  u16* lB0 = smem + 16384;                     // [512][64] = 64 KB
  u16* lB1 = smem + 49152;

  const int tid = threadIdx.x;
  const int lane = tid & 63, wv = tid >> 6;
  const int wr = wv >> 2, wc = wv & 3;         // 2M x 4N waves
  const int fr = lane & 15, fq = lane >> 4;
  const int by = blockIdx.x;                   // m-tile 0..31
  const int bz = blockIdx.z;                   // batchInPair*4 + chunk
  const int bzb = bz >> 2;
  const int tb = (bz & 3) * (K >> 6);

  const u16* Ab = A + (long)bzb * asb + (long)(by * 128) * lda;
  const u16* Bb = Bt + (long)bzb * bsb;

  // A half-tile = 64 rows x 64 cols = 1 gload/thread
  auto stageA = [&](u16* lbase, int half, int t) {
    int row = tid >> 3, ch = tid & 7;
    int src = t * 64 + ((((ch << 4) ^ ((row & 7) << 4))) >> 1);
    gload16(Ab + (long)(half * 64 + row) * lda + src,
            lbase + half * 4096 + tid * 8);
  };
  // B half-tile = 256 rows x 64 cols = 4 gloads/thread
  auto stageB = [&](u16* lbase, int half, int t) {
#pragma unroll
    for (int p = 0; p < 4; ++p) {
      int i = p * 512 + tid;
      int row = i >> 3, ch = i & 7;
      int src = t * 64 + ((((ch << 4) ^ ((row & 7) << 4))) >> 1);
      gload16(Bb + (long)(half * 256 + row) * ldb + src,
              lbase + half * 16384 + i * 8);
    }
  };

  f32x4 acc[4][8];
#pragma unroll
  for (int m = 0; m < 4; ++m)
#pragma unroll
    for (int n = 0; n < 8; ++n) acc[m][n] = (f32x4)(0.f);

  // prologue: A(T0), B(T0), A(T1); leave A(T1)'s 2 loads in flight
  stageA(lA0, 0, tb); stageA(lA0, 1, tb);
  stageB(lB0, 0, tb); stageB(lB0, 1, tb);
  stageA(lA1, 0, tb + 1); stageA(lA1, 1, tb + 1);
  asm volatile("s_waitcnt vmcnt(2)" ::: "memory");
  __builtin_amdgcn_sched_barrier(0);
  __builtin_amdgcn_s_barrier();

  const int nt = K >> 6;                       // 16
  short8 af[4][2], bq[2][2];
  for (int i = 0; i < nt / 2; ++i) {
    const bool last = (i == nt / 2 - 1);
    const int t1 = tb + 2 * i + 1, t2 = tb + 2 * i + 2, t3 = tb + 2 * i + 3;
    // ---- Ta from lA0/lB0 ----
    rdAall(lA0, wr, fr, fq, af);
    rdB2<0>(lB0, wc, fr, fq, bq);
    stageB(lB1, 0, t1);
    PTAILW(0)
    rdB2<1>(lB0, wc, fr, fq, bq);
    stageB(lB1, 1, t1);
    PTAILW(1)
    rdB2<2>(lB0, wc, fr, fq, bq);
    if (!last) stageA(lA0, 0, t2);
    PTAILW(2)
    rdB2<3>(lB0, wc, fr, fq, bq);
    if (!last) stageA(lA0, 1, t2);
    if (last) { asm volatile("s_waitcnt vmcnt(0)" ::: "memory"); }
    else      { asm volatile("s_waitcnt vmcnt(2)" ::: "memory"); }
    __builtin_amdgcn_sched_barrier(0);
    PTAILW(3)
    // ---- Tb from lA1/lB1 ----
    rdAall(lA1, wr, fr, fq, af);
    rdB2<0>(lB1, wc, fr, fq, bq);
    if (!last) stageB(lB0, 0, t2);
    PTAILW(0)
    rdB2<1>(lB1, wc, fr, fq, bq);
    if (!last) stageB(lB0, 1, t2);
    PTAILW(1)
    rdB2<2>(lB1, wc, fr, fq, bq);
    if (!last) stageA(lA1, 0, t3);
    PTAILW(2)
    rdB2<3>(lB1, wc, fr, fq, bq);
    if (!last) stageA(lA1, 1, t3);
    if (!last) {
      asm volatile("s_waitcnt vmcnt(2)" ::: "memory");
      __builtin_amdgcn_sched_barrier(0);
    }
    PTAILW(3)
  }

  // ---- fused rls: threads<128 sum 16 spp slices for this block's rows ----
  float* rlb = (float*)(smem + 73728);         // 512 B beyond repack region
  if (tid < 128) {
    const float* sp = spp + (long)bzb * 16 * LL + by * 128 + tid;
    float s = 0.f;
#pragma unroll
    for (int j = 0; j < 16; ++j) s += sp[(long)j * LL];
    rlb[tid] = 1.0f / s;
  }
  __syncthreads();

  // ---- epilogue: bf16(acc * rl[row]) -> [128][512] tile, 16B stores ----
#pragma unroll
  for (int mf = 0; mf < 4; ++mf)
#pragma unroll
    for (int nf = 0; nf < 8; ++nf) {
      const int nl = wc * 128 + nf * 16 + fr;
#pragma unroll
      for (int r = 0; r < 4; ++r) {
        const int ml = wr * 64 + mf * 16 + fq * 4 + r;
        smem[ml * 512 + (nl ^ ((ml & 7) << 3))] =
            f2bf(acc[mf][nf][r] * rlb[ml]);
      }
    }
  __syncthreads();
  u16* dst0 = o0 + (long)bzb * 4 * NELC + (long)(by * 128) * ldo + (bz & 3) * 512;
  for (int i = tid * 8; i < 65536; i += 4096) {
    const int rr = i >> 9, cc = i & 511;
    short8 val = *(const short8*)&smem[rr * 512 + (cc ^ ((rr & 7) << 3))];
    *(short8*)(dst0 + (long)rr * ldo + cc) = val;
  }
}

// ---------------------------------------------------------------------------
// m97-style GEMM skeleton (out-projection; PV fallback for G=1).
// EPI: 3=out (fp32 +bias +residual)   4=PV split-K normalized (G=1 fallback)
// ---------------------------------------------------------------------------
template <int BM, int BN, int EPI, bool SWZ, int WR, int WC>
__global__ __launch_bounds__(WR * WC * 64) void gemm_bt(
    const u16* __restrict__ A, int lda, long asb,
    const u16* __restrict__ Bt, int ldb, long bsb,
    int K, const float* __restrict__ bias, float scale,
    u16* __restrict__ o0, u16* __restrict__ o1, u16* __restrict__ o2,
    float* __restrict__ of, const float* __restrict__ xres, long osb, int ldo) {
  constexpr int NT = WR * WC * 64;
  constexpr int FM = BM / WR / 16, FN = BN / WC / 16;
  static_assert((BM * 8) % NT == 0 && (BN * 8) % NT == 0, "staging div");
  __shared__ u16 smem[(BM + BN) * 64];
  u16* lA = smem;
  u16* lB = smem + BM * 64;

  int bx = blockIdx.x, by = blockIdx.y;
  if constexpr (SWZ) {
    const int nwg = gridDim.x * gridDim.y;
    const int id = by * gridDim.x + bx;
    const int id2 = (id & 7) * (nwg >> 3) + (id >> 3);
    bx = id2 % gridDim.x;
    by = id2 / gridDim.x;
  }

  const int tid = threadIdx.x;
  const int lane = tid & 63;
  const int wv = tid >> 6;
  const int wr = wv / WC, wc = wv % WC;
  const int fr = lane & 15, fq = lane >> 4;
  const int bz = blockIdx.z;
  const int bzb  = (EPI == 4) ? (bz >> 1) : bz;
  const int kbeg = (EPI == 4) ? (bz & 1) * K : 0;

  const u16* Ab = A + (long)bzb * asb + (long)(by * BM) * lda;
  const u16* Bb = Bt + (long)bzb * bsb + (long)(bx * BN) * ldb;

  f32x4 acc[FM][FN];
#pragma unroll
  for (int m = 0; m < FM; ++m)
#pragma unroll
    for (int n = 0; n < FN; ++n) acc[m][n] = (f32x4)(0.f);

  for (int k0 = kbeg; k0 < kbeg + K; k0 += 64) {
#pragma unroll
    for (int p = 0; p < BM * 8 / NT; ++p) {
      int t = p * NT + tid;
      int row = t >> 3;
      int cbl = ((t & 7) << 4) ^ ((row & 7) << 4);
      gload16(Ab + (long)row * lda + k0 + (cbl >> 1), &lA[t * 8]);
    }
#pragma unroll
    for (int p = 0; p < BN * 8 / NT; ++p) {
      int t = p * NT + tid;
      int row = t >> 3;
      int cbl = ((t & 7) << 4) ^ ((row & 7) << 4);
      gload16(Bb + (long)row * ldb + k0 + (cbl >> 1), &lB[t * 8]);
    }
    __syncthreads();
#pragma unroll
    for (int ks = 0; ks < 2; ++ks) {
      short8 af[FM], bfr[FN];
#pragma unroll
      for (int m = 0; m < FM; ++m) {
        int row = wr * (BM / WR) + m * 16 + fr;
        int cb = (ks * 64 + fq * 16) ^ ((row & 7) << 4);
        af[m] = *(const short8*)((const char*)lA + row * 128 + cb);
      }
#pragma unroll
      for (int n = 0; n < FN; ++n) {
        int row = wc * (BN / WC) + n * 16 + fr;
        int cb = (ks * 64 + fq * 16) ^ ((row & 7) << 4);
        bfr[n] = *(const short8*)((const char*)lB + row * 128 + cb);
      }
#pragma unroll
      for (int m = 0; m < FM; ++m)
#pragma unroll
        for (int n = 0; n < FN; ++n)
          acc[m][n] = __builtin_amdgcn_mfma_f32_16x16x32_bf16(af[m], bfr[n], acc[m][n], 0, 0, 0);
    }
    __syncthreads();
  }

  const int ml0 = wr * (BM / WR);
  const int nl0 = wc * (BN / WC);

  if constexpr (EPI == 3) {
    const int mg0 = by * BM + ml0;
    const int ng0 = bx * BN + nl0;
#pragma unroll
    for (int m = 0; m < FM; ++m)
#pragma unroll
      for (int n = 0; n < FN; ++n) {
        const int ng = ng0 + n * 16 + fr;
#pragma unroll
        for (int r = 0; r < 4; ++r) {
          const int mg = mg0 + m * 16 + fq * 4 + r;
          const long off = (long)bz * osb + (long)mg * ldo + ng;
          of[off] = acc[m][n][r] + bias[mg] + xres[off];
        }
      }
  } else {
    const float* rls = xres + (long)(bz >> 1) * LL + by * BM;
#pragma unroll
    for (int m = 0; m < FM; ++m)
#pragma unroll
      for (int n = 0; n < FN; ++n) {
        const int nl = nl0 + n * 16 + fr;
#pragma unroll
        for (int r = 0; r < 4; ++r) {
          const int ml = ml0 + m * 16 + fq * 4 + r;
          smem[ml * BN + (nl ^ ((ml & 7) << 3))] = f2bf(acc[m][n][r] * rls[ml]);
        }
      }
    __syncthreads();
    u16* dst0 = ((bz & 1) ? o1 : o0) + (long)(bz >> 1) * NELC +
                (long)(by * BM) * ldo + bx * BN;
    for (int i = tid * 8; i < BM * BN; i += NT * 8) {
      const int rr = i / BN, cc = i % BN;
      short8 val = *(const short8*)&smem[rr * BN + (cc ^ ((rr & 7) << 3))];
      *(short8*)(dst0 + (long)rr * ldo + cc) = val;
    }
  }
}

// ---------------------------------------------------------------------------
// K4 (G=1 fallback): rls[z][i] = 1 / sum_{j<16} spp[z][j][i]
// ---------------------------------------------------------------------------
__global__ __launch_bounds__(256) void rls_combine(const float* __restrict__ spp,
                                                   float* __restrict__ rls) {
  const int row = blockIdx.x * 256 + threadIdx.x;
  const int z = blockIdx.y;
  const float* b = spp + (long)z * 16 * LL + row;
  float s = 0.f;
#pragma unroll
  for (int j = 0; j < 16; ++j) s += b[(long)j * LL];
  rls[(long)z * LL + row] = 1.0f / s;
}

// ---------------------------------------------------------------------------
// K5: sum 4 interleaved chunk-partials [4096][2048] -> [4096][512] bf16.
// ---------------------------------------------------------------------------
__global__ __launch_bounds__(256) void reduce4(
    const u16* __restrict__ P, u16* __restrict__ o) {
  const int b = blockIdx.y;
  const long idx = (long)blockIdx.x * 256 + threadIdx.x;
  const int i = (int)(idx >> 6);
  const int c0 = ((int)idx & 63) * 8;
  const u16* Pb = P + (long)b * 4 * NELC + (long)i * 2048;
  float s[8] = {0.f, 0.f, 0.f, 0.f, 0.f, 0.f, 0.f, 0.f};
#pragma unroll
  for (int c4 = 0; c4 < 4; ++c4) {
    short8 v = *(const short8*)(Pb + c4 * 512 + c0);
#pragma unroll
    for (int j = 0; j < 8; ++j) s[j] += bf2f((u16)v[j]);
  }
  short8 r;
#pragma unroll
  for (int j = 0; j < 8; ++j) r[j] = (short)f2bf(s[j]);
  *(short8*)(o + (long)b * NELC + (long)i * 512 + c0) = r;
}

// ---------------------------------------------------------------------------
// K6 (G=1 fallback): sum two bf16 partial planes -> bf16 out plane.
// ---------------------------------------------------------------------------
__global__ __launch_bounds__(256) void reduce_pp(
    const u16* __restrict__ p0, const u16* __restrict__ p1, u16* __restrict__ o) {
  const long base = (long)blockIdx.y * NELC +
                    (long)(blockIdx.x * 256 + threadIdx.x) * 16;
#pragma unroll
  for (int h = 0; h < 2; ++h) {
    short8 a = *(const short8*)(p0 + base + h * 8);
    short8 b = *(const short8*)(p1 + base + h * 8);
    short8 r;
#pragma unroll
    for (int j = 0; j < 8; ++j)
      r[j] = (short)f2bf(bf2f((u16)a[j]) + bf2f((u16)b[j]));
    *(short8*)(o + base + h * 8) = r;
  }
}

// ---------------------------------------------------------------------------
extern "C" void kernel_launch(void* const* d_in, const int* in_sizes, int n_in,
                              void* d_out, int out_size, void* d_ws, size_t ws_size,
                              hipStream_t stream) {
  const float* x   = (const float*)d_in[0];
  const float* gnw = (const float*)d_in[1];
  const float* gnb = (const float*)d_in[2];
  const float* wq  = (const float*)d_in[3];
  const float* bq  = (const float*)d_in[4];
  const float* wk  = (const float*)d_in[5];
  const float* bk  = (const float*)d_in[6];
  const float* wv  = (const float*)d_in[7];
  const float* bv  = (const float*)d_in[8];
  const float* wo  = (const float*)d_in[9];
  const float* bo  = (const float*)d_in[10];
  float* out = (float*)d_out;

  char* ws = (char*)d_ws;
  const long NEL = NELC;
  const long SEL = (long)LL * LL;
  float* stats = (float*)ws;                               // 8 KB
  float* bqkv  = (float*)(ws + 8192);                      // 6 KB
  u16* wqkv = (u16*)(ws + 16384);                          // 1.5 MB
  u16* wob  = (u16*)(ws + 16384 + 1572864);                // 0.5 MB (ends 2113536)
  float* spp  = (float*)(ws + 2113536);                    // 512 KB (16-slice sums)
  float* rlsm = (float*)(ws + (3l << 20));                 // 16 KB (G=1 path)
  u16* hT   = (u16*)(ws + (4l << 20));                     // 32 MB; PV partials after QKV
  u16* qT   = hT + 8 * NEL;                                // 32 MB  [B][L][C]
  u16* kT   = qT + 8 * NEL;                                // 32 MB  [B][L][C]
  u16* vN   = kT + 8 * NEL;                                // 32 MB  [B][C][L]
  const size_t base = (4ul << 20) + 4ul * 8 * NEL * 2;     // 132 MB

  const int G = (ws_size >= base + 2ul * SEL * 2) ? 2 : 1;
  u16* Sbuf = (G == 2) ? (u16*)(ws + base) : hT;

  prep<<<1281, 256, 0, stream>>>(wq, wk, wv, wo, bq, bk, bv, x,
                                 wqkv, wob, bqkv, stats);
  gn_apply<<<dim3(64, 8, 8), 256, 0, stream>>>(x, gnw, gnb, stats, hT);

  // fused QKV, 8-phase 256^2: A=wqkv [1536][512], Bt=hT[b] [4096][512]
  gemm8p<0><<<dim3(16, 6, 8), 512, 0, stream>>>(
      wqkv, 512, 0, hT, 512, NEL, 512, bqkv, 1.f, qT, kT, vN,
      nullptr, 0, 0);

  // no-max softmax (numerics proven r6/r7): expS = exp2(cl * q.k)
  const float cl = (1.0f / sqrtf(512.0f)) * 1.44269504f;
  for (int g0 = 0; g0 < 8; g0 += G) {
    // expS[z] = exp2(cl * qT[g0+z] * kT[g0+z]^T), 8-phase + store-loop row sums
    gemm8p<1><<<dim3(16, 16, G), 512, 0, stream>>>(
        qT + (long)g0 * NEL, 512, NEL, kT + (long)g0 * NEL, 512, NEL, 512,
        nullptr, cl, Sbuf, nullptr, nullptr, spp, SEL, LL);
    if (G == 2) {
      // PV wide-B 8-phase split-K=4 (S staged once; rls fused in-kernel):
      // A=Sbuf [4096][4096], Bt=vN [512][4096]; 256 blocks.
      gemm8pw<<<dim3(32, 1, 8), 512, 0, stream>>>(
          Sbuf, LL, SEL, vN + (long)g0 * NEL, LL, NEL, 1024, hT, spp, 2048);
      reduce4<<<dim3(1024, 2), 256, 0, stream>>>(hT, qT + (long)g0 * NEL);
    } else {
      rls_combine<<<dim3(16, 1), 256, 0, stream>>>(spp, rlsm);
      gemm_bt<128, 128, 4, true, 2, 4><<<dim3(4, 32, 2), 512, 0, stream>>>(
          Sbuf, LL, SEL, vN + (long)g0 * NEL, LL, NEL, 2048,
          nullptr, 1.f, qT + (long)g0 * NEL, kT + (long)g0 * NEL, nullptr,
          nullptr, rlsm, 0, CB);
      reduce_pp<<<dim3(512, 1), 256, 0, stream>>>(
          qT + (long)g0 * NEL, kT + (long)g0 * NEL, qT + (long)g0 * NEL);
    }
  }

  // out = x + wo * attn^T + bo : attn planes live in qT; M=512, N=4096, K=512
  gemm_bt<128, 128, 3, false, 2, 2><<<dim3(32, 4, 8), 256, 0, stream>>>(
      wob, 512, 0, qT, 512, NEL, 512, bo, 1.f,
      nullptr, nullptr, nullptr, out, x, NEL, LL);

  (void)in_sizes; (void)n_in; (void)out_size; (void)ws_size;
}

// Round 17
// 559.735 us; speedup vs baseline: 1.0321x; 1.0321x over previous
//
#include <hip/hip_runtime.h>
#include <hip/hip_bf16.h>
#include <math.h>

#define DI __device__ __forceinline__

typedef unsigned short u16;
typedef unsigned int   u32;
typedef unsigned long long u64;
typedef __attribute__((ext_vector_type(8))) short short8;   // 8 bf16 (4 VGPRs) MFMA A/B frag
typedef __attribute__((ext_vector_type(4))) float f32x4;    // MFMA C/D frag

constexpr int CB = 512;    // channels
constexpr int LL = 4096;   // length
constexpr int NG = 32;     // groups
constexpr long NELC = (long)LL * CB;       // elems per [l][c] plane

DI float bf2f(u16 u) { u32 v = ((u32)u) << 16; float f; __builtin_memcpy(&f, &v, 4); return f; }
DI u16 f2bf(float f) {
  u32 u; __builtin_memcpy(&u, &f, 4);
  u += 0x7fffu + ((u >> 16) & 1u);   // RNE
  return (u16)(u >> 16);
}

DI void gload16(const void* g, void* l) {
  __builtin_amdgcn_global_load_lds((const __attribute__((address_space(1))) u32*)g,
                                   (__attribute__((address_space(3))) u32*)l, 16, 0, 0);
}

// ---------------------------------------------------------------------------
// K0: prep = conv_w (weights->bf16, fused bias) UNION gn_stats (one dispatch).
// ---------------------------------------------------------------------------
__global__ __launch_bounds__(256) void prep(
    const float* __restrict__ wq, const float* __restrict__ wk,
    const float* __restrict__ wv, const float* __restrict__ wo,
    const float* __restrict__ bq, const float* __restrict__ bk,
    const float* __restrict__ bv, const float* __restrict__ x,
    u16* __restrict__ wqkv, u16* __restrict__ wob, float* __restrict__ bqkv,
    float* __restrict__ stats) {
  if (blockIdx.x < 1024) {
    int i = blockIdx.x * 256 + threadIdx.x;
    wqkv[i]          = f2bf(wq[i]);
    wqkv[262144 + i] = f2bf(wk[i]);
    wqkv[524288 + i] = f2bf(wv[i]);
    wob[i]           = f2bf(wo[i]);
  } else if (blockIdx.x == 1024) {
    for (int j = 0; j < 6; ++j) {
      int idx = j * 256 + threadIdx.x;
      float b = (idx < 512) ? bq[idx] : (idx < 1024) ? bk[idx - 512] : bv[idx - 1024];
      bqkv[idx] = b;
    }
  } else {
    const int bid = blockIdx.x - 1025;            // 0..255 = (b,g)
    const float4* base = (const float4*)(x + (long)bid * (16 * LL));
    float s = 0.f, ss = 0.f;
    for (int i = threadIdx.x; i < 16 * LL / 4; i += 256) {
      float4 v = base[i];
      s  += v.x + v.y + v.z + v.w;
      ss += v.x * v.x + v.y * v.y + v.z * v.z + v.w * v.w;
    }
#pragma unroll
    for (int o = 32; o; o >>= 1) { s += __shfl_xor(s, o); ss += __shfl_xor(ss, o); }
    __shared__ float red[8];
    int wv2 = threadIdx.x >> 6, ln = threadIdx.x & 63;
    if (ln == 0) { red[wv2 * 2] = s; red[wv2 * 2 + 1] = ss; }
    __syncthreads();
    if (threadIdx.x == 0) {
      float S = red[0] + red[2] + red[4] + red[6];
      float SS = red[1] + red[3] + red[5] + red[7];
      float mu = S * (1.f / 65536.f);
      float var = SS * (1.f / 65536.f) - mu * mu;
      stats[bid * 2]     = mu;
      stats[bid * 2 + 1] = rsqrtf(var + 1e-6f);
    }
  }
}

// ---------------------------------------------------------------------------
// K2: GroupNorm apply + transpose (vectorized): hT[b][l][c] = bf16(gn(x))
// ---------------------------------------------------------------------------
__global__ __launch_bounds__(256) void gn_apply(
    const float* __restrict__ x, const float* __restrict__ gw,
    const float* __restrict__ gb, const float* __restrict__ stats,
    u16* __restrict__ hT) {
  __shared__ u16 t[64][66];                      // [c][l] padded tile
  const int b = blockIdx.z, c0 = blockIdx.y * 64, l0 = blockIdx.x * 64;
  const int tid = threadIdx.x;
#pragma unroll
  for (int p = 0; p < 4; ++p) {
    const int cr = p * 16 + (tid >> 4);
    const int lq = (tid & 15) * 4;
    const int c = c0 + cr;
    const float mu = stats[(b * NG + (c >> 4)) * 2];
    const float rs = stats[(b * NG + (c >> 4)) * 2 + 1];
    const float g = gw[c], be = gb[c];
    float4 v = *(const float4*)(x + (long)b * CB * LL + (long)c * LL + l0 + lq);
    t[cr][lq + 0] = f2bf((v.x - mu) * rs * g + be);
    t[cr][lq + 1] = f2bf((v.y - mu) * rs * g + be);
    t[cr][lq + 2] = f2bf((v.z - mu) * rs * g + be);
    t[cr][lq + 3] = f2bf((v.w - mu) * rs * g + be);
  }
  __syncthreads();
#pragma unroll
  for (int it = 0; it < 2; ++it) {
    const int i = it * 2048 + tid * 8;           // element id within 64x64
    const int lr = i >> 6, cc = i & 63;
    short8 val;
#pragma unroll
    for (int j = 0; j < 8; ++j) val[j] = (short)t[cc + j][lr];
    *(short8*)(hT + (long)b * LL * CB + (long)(l0 + lr) * CB + c0 + cc) = val;
  }
}

// ---------------------------------------------------------------------------
// 8-phase 256x256 GEMM (HK schedule, plain HIP): D = A[M][K] * Bt[N][K]^T.
// 8 waves (2M x 4N), per-wave 128x64 output (acc[8][4]); BK=64 K-tiles;
// 2 dbuf x {A,B} LDS regions (4 x 32 KB), XOR-swizzled staging
// (linear gload_lds dest + pre-swizzled source, rule #21).
// Schedule (race-free; region staged only after its death barrier):
//   iter i reads Ta=T(2i) [ph1-4, lA0/lB0], Tb=T(2i+1) [ph5-8, lA1/lB1].
//   stages: ph1,2 -> lA1 (T2i+1); ph3,4 -> lB0 (T2i+2);
//           ph5,6 -> lA0 (T2i+2); ph7,8 -> lB1 (T2i+3).
//   vmcnt(4) at ph4 & ph8; last iter vmcnt(0) at ph4.
// EPI: 0 = QKV (by: 0,1=q 2,3=k -> [l][c] transposed; 4,5=v -> [c][l]; +bias)
//      1 = expS (bf16(exp2(acc*scale))); row sums computed REGISTER-NEUTRALLY
//          in the store loop (r12/r13 spill lesson) -> spp[z][bx][row]
//      2 = PV split-K partial: bz=(batch<<2)|chunk, natural raster (r12: XCD
//          grouping hurt; r16: wide-B hurt); rls FUSED in epilogue: rlb[256]
//          = 1/sum(spp slices) computed in 1KB LDS extension post-main-loop
//          (register-neutral; identical fp32 sum order to old rls_combine);
//          store bf16(acc*rlb[row]) -> per-batch [4096][2048] chunk-interleaved.
// ---------------------------------------------------------------------------
template <int Q>
DI void rdA(const u16* LB, int wr, int fr, int fq, short8 af[2][2]) {
#pragma unroll
  for (int m2 = 0; m2 < 2; ++m2)
#pragma unroll
    for (int kk = 0; kk < 2; ++kk) {
      const int R = wr * 128 + (Q * 2 + m2) * 16 + fr;
      af[m2][kk] = *(const short8*)((const char*)LB + R * 128 +
                                    ((kk * 64 + fq * 16) ^ ((R & 7) << 4)));
    }
}
DI void rdB(const u16* LB, int wc, int fr, int fq, short8 bf[4][2]) {
#pragma unroll
  for (int nf = 0; nf < 4; ++nf)
#pragma unroll
    for (int kk = 0; kk < 2; ++kk) {
      const int R = wc * 64 + nf * 16 + fr;
      bf[nf][kk] = *(const short8*)((const char*)LB + R * 128 +
                                    ((kk * 64 + fq * 16) ^ ((R & 7) << 4)));
    }
}
template <int Q>
DI void mmaQ(short8 af[2][2], short8 bf[4][2], f32x4 acc[8][4]) {
#pragma unroll
  for (int kk = 0; kk < 2; ++kk)
#pragma unroll
    for (int m2 = 0; m2 < 2; ++m2)
#pragma unroll
      for (int nf = 0; nf < 4; ++nf)
        acc[Q * 2 + m2][nf] = __builtin_amdgcn_mfma_f32_16x16x32_bf16(
            af[m2][kk], bf[nf][kk], acc[Q * 2 + m2][nf], 0, 0, 0);
}

#define PTAIL(Q)                                             \
  __builtin_amdgcn_s_barrier();                              \
  asm volatile("s_waitcnt lgkmcnt(0)" ::: "memory");         \
  __builtin_amdgcn_sched_barrier(0);                         \
  __builtin_amdgcn_s_setprio(1);                             \
  mmaQ<Q>(af, bf, acc);                                      \
  __builtin_amdgcn_s_setprio(0);                             \
  __builtin_amdgcn_s_barrier();

template <int EPI>
__global__ __launch_bounds__(512, 2) void gemm8p(
    const u16* __restrict__ A, int lda, long asb,
    const u16* __restrict__ Bt, int ldb, long bsb,
    int K, const float* __restrict__ bias, float scale,
    u16* __restrict__ o0, u16* __restrict__ o1, u16* __restrict__ o2,
    float* __restrict__ spp, long osb, int ldo) {
  __shared__ u16 smem[66048];                  // 128 KB tile regions + 1 KB rlb
  u16* lA0 = smem;                             // [256][64] per region
  u16* lA1 = smem + 16384;
  u16* lB0 = smem + 32768;
  u16* lB1 = smem + 49152;

  const int tid = threadIdx.x;
  const int lane = tid & 63, wv = tid >> 6;
  const int wr = wv >> 2, wc = wv & 3;         // 2 x 4 waves
  const int fr = lane & 15, fq = lane >> 4;
  const int bx = blockIdx.x, by = blockIdx.y, bz = blockIdx.z;
  const int bzb = (EPI == 2) ? (bz >> 2) : bz;           // batch
  const int tb  = (EPI == 2) ? (bz & 3) * (K >> 6) : 0;  // chunk tile base

  const u16* Ab = A + (long)bzb * asb + (long)(by * 256) * lda;
  const u16* Bb = Bt + (long)bzb * bsb + (long)(bx * 256) * ldb;

  // stage one half-tile (128 rows x 64 cols) = 2 gload_lds / thread
  auto stage = [&](u16* lbase, const u16* gbase, int ld_, int half, int t) {
#pragma unroll
    for (int p = 0; p < 2; ++p) {
      int i = p * 512 + tid;
      int row = i >> 3, ch = i & 7;
      int src = t * 64 + ((((ch << 4) ^ ((row & 7) << 4))) >> 1);
      gload16(gbase + (long)(half * 128 + row) * ld_ + src,
              lbase + half * 8192 + i * 8);
    }
  };

  f32x4 acc[8][4];
#pragma unroll
  for (int m = 0; m < 8; ++m)
#pragma unroll
    for (int n = 0; n < 4; ++n) acc[m][n] = (f32x4)(0.f);

  // prologue: A(T0), B(T0), B(T1); wait all but B(T1)'s 4 loads
  stage(lA0, Ab, lda, 0, tb); stage(lA0, Ab, lda, 1, tb);
  stage(lB0, Bb, ldb, 0, tb); stage(lB0, Bb, ldb, 1, tb);
  stage(lB1, Bb, ldb, 0, tb + 1); stage(lB1, Bb, ldb, 1, tb + 1);
  asm volatile("s_waitcnt vmcnt(4)" ::: "memory");
  __builtin_amdgcn_sched_barrier(0);
  __builtin_amdgcn_s_barrier();

  const int nt = K >> 6;                       // K-tiles (even, >= 4)
  short8 af[2][2], bf[4][2];
  for (int i = 0; i < nt / 2; ++i) {
    const bool last = (i == nt / 2 - 1);
    const int t1 = tb + 2 * i + 1, t2 = tb + 2 * i + 2, t3 = tb + 2 * i + 3;
    // ---- Ta = T(2i) from lA0/lB0 ----
    rdB(lB0, wc, fr, fq, bf);
    rdA<0>(lA0, wr, fr, fq, af);
    stage(lA1, Ab, lda, 0, t1);
    PTAIL(0)
    rdA<1>(lA0, wr, fr, fq, af);
    stage(lA1, Ab, lda, 1, t1);
    PTAIL(1)
    rdA<2>(lA0, wr, fr, fq, af);
    if (!last) stage(lB0, Bb, ldb, 0, t2);
    PTAIL(2)
    rdA<3>(lA0, wr, fr, fq, af);
    if (!last) stage(lB0, Bb, ldb, 1, t2);
    if (last) { asm volatile("s_waitcnt vmcnt(0)" ::: "memory"); }
    else      { asm volatile("s_waitcnt vmcnt(4)" ::: "memory"); }
    __builtin_amdgcn_sched_barrier(0);
    PTAIL(3)
    // ---- Tb = T(2i+1) from lA1/lB1 ----
    rdB(lB1, wc, fr, fq, bf);
    rdA<0>(lA1, wr, fr, fq, af);
    if (!last) stage(lA0, Ab, lda, 0, t2);
    PTAIL(0)
    rdA<1>(lA1, wr, fr, fq, af);
    if (!last) stage(lA0, Ab, lda, 1, t2);
    PTAIL(1)
    rdA<2>(lA1, wr, fr, fq, af);
    if (!last) stage(lB1, Bb, ldb, 0, t3);
    PTAIL(2)
    rdA<3>(lA1, wr, fr, fq, af);
    if (!last) stage(lB1, Bb, ldb, 1, t3);
    if (!last) {
      asm volatile("s_waitcnt vmcnt(4)" ::: "memory");
      __builtin_amdgcn_sched_barrier(0);
    }
    PTAIL(3)
  }

  // ---- epilogue: repack 256x256 tile through smem, 16B stores ----
  if constexpr (EPI == 1) {
    // expS: bf16(exp2(acc*scale)), row-major [m][n]  (acc loop register-lean)
#pragma unroll
    for (int mf = 0; mf < 8; ++mf)
#pragma unroll
      for (int nf = 0; nf < 4; ++nf) {
        const int nl = wc * 64 + nf * 16 + fr;
#pragma unroll
        for (int r = 0; r < 4; ++r) {
          const int ml = wr * 128 + mf * 16 + fq * 4 + r;
          smem[ml * 256 + (nl ^ ((ml & 7) << 3))] =
              f2bf(exp2f(acc[mf][nf][r] * scale));
        }
      }
    __syncthreads();
    u16* dst0 = o0 + (long)bz * osb + (long)(by * 256) * ldo + bx * 256;
    float* sppb = spp + ((long)bz * 16 + bx) * LL + by * 256;
    for (int i = tid * 8; i < 65536; i += 4096) {
      const int rr = i >> 8, cc = i & 255;
      short8 val = *(const short8*)&smem[rr * 256 + (cc ^ ((rr & 7) << 3))];
      *(short8*)(dst0 + (long)rr * ldo + cc) = val;
      // register-neutral row-sum: 32 consecutive lanes share row rr
      float s = 0.f;
#pragma unroll
      for (int j = 0; j < 8; ++j) s += bf2f((u16)val[j]);
      s += __shfl_xor(s, 1);  s += __shfl_xor(s, 2);
      s += __shfl_xor(s, 4);  s += __shfl_xor(s, 8);
      s += __shfl_xor(s, 16);
      if ((tid & 31) == 0) sppb[rr] = s;
    }
  } else if constexpr (EPI == 2) {
    // fused rls: rlb[256] in the 1KB LDS extension (identical sum order to
    // the old rls_combine kernel -> bit-identical normalization)
    float* rlb = (float*)(smem + 65536);
    if (tid < 256) {
      const float* sp = spp + (long)bzb * 16 * LL + by * 256 + tid;
      float s = 0.f;
#pragma unroll
      for (int j = 0; j < 16; ++j) s += sp[(long)j * LL];
      rlb[tid] = 1.0f / s;
    }
    __syncthreads();
    // PV split-K partial, normalized: bf16(acc * rlb[row]) -> [4096][2048]
#pragma unroll
    for (int mf = 0; mf < 8; ++mf)
#pragma unroll
      for (int nf = 0; nf < 4; ++nf) {
        const int nl = wc * 64 + nf * 16 + fr;
#pragma unroll
        for (int r = 0; r < 4; ++r) {
          const int ml = wr * 128 + mf * 16 + fq * 4 + r;
          smem[ml * 256 + (nl ^ ((ml & 7) << 3))] =
              f2bf(acc[mf][nf][r] * rlb[ml]);
        }
      }
    __syncthreads();
    u16* dst0 = o0 + (long)bzb * 4 * NELC + (long)(by * 256) * 2048 +
                (bz & 3) * 512 + bx * 256;
    for (int i = tid * 8; i < 65536; i += 4096) {
      const int rr = i >> 8, cc = i & 255;
      short8 val = *(const short8*)&smem[rr * 256 + (cc ^ ((rr & 7) << 3))];
      *(short8*)(dst0 + (long)rr * 2048 + cc) = val;
    }
  } else {
    // QKV: by 0,1 -> q; 2,3 -> k (transposed [l][c]); 4,5 -> v (natural [c][l])
    const int mat = by >> 1;
    if (mat < 2) {
#pragma unroll
      for (int mf = 0; mf < 8; ++mf)
#pragma unroll
        for (int nf = 0; nf < 4; ++nf) {
          const int nl = wc * 64 + nf * 16 + fr;
#pragma unroll
          for (int r = 0; r < 4; ++r) {
            const int ml = wr * 128 + mf * 16 + fq * 4 + r;
            smem[nl * 256 + (ml ^ ((nl & 7) << 3))] =
                f2bf(acc[mf][nf][r] + bias[by * 256 + ml]);
          }
        }
      __syncthreads();
      u16* dst0 = (mat == 0 ? o0 : o1) + (long)bz * NELC +
                  (long)(bx * 256) * CB + ((by * 256) & 511);
      for (int i = tid * 8; i < 65536; i += 4096) {
        const int rr = i >> 8, cc = i & 255;
        short8 val = *(const short8*)&smem[rr * 256 + (cc ^ ((rr & 7) << 3))];
        *(short8*)(dst0 + (long)rr * CB + cc) = val;
      }
    } else {
#pragma unroll
      for (int mf = 0; mf < 8; ++mf)
#pragma unroll
        for (int nf = 0; nf < 4; ++nf) {
          const int nl = wc * 64 + nf * 16 + fr;
#pragma unroll
          for (int r = 0; r < 4; ++r) {
            const int ml = wr * 128 + mf * 16 + fq * 4 + r;
            smem[ml * 256 + (nl ^ ((ml & 7) << 3))] =
                f2bf(acc[mf][nf][r] + bias[by * 256 + ml]);
          }
        }
      __syncthreads();
      u16* dst0 = o2 + (long)bz * ((long)CB * LL) +
                  (long)((by * 256) & 511) * LL + bx * 256;
      for (int i = tid * 8; i < 65536; i += 4096) {
        const int rr = i >> 8, cc = i & 255;
        short8 val = *(const short8*)&smem[rr * 256 + (cc ^ ((rr & 7) << 3))];
        *(short8*)(dst0 + (long)rr * LL + cc) = val;
      }
    }
  }
}

// ---------------------------------------------------------------------------
// m97-style GEMM skeleton (out-projection; PV fallback for G=1).
// EPI: 3=out (fp32 +bias +residual)   4=PV split-K normalized (G=1 fallback)
// ---------------------------------------------------------------------------
template <int BM, int BN, int EPI, bool SWZ, int WR, int WC>
__global__ __launch_bounds__(WR * WC * 64) void gemm_bt(
    const u16* __restrict__ A, int lda, long asb,
    const u16* __restrict__ Bt, int ldb, long bsb,
    int K, const float* __restrict__ bias, float scale,
    u16* __restrict__ o0, u16* __restrict__ o1, u16* __restrict__ o2,
    float* __restrict__ of, const float* __restrict__ xres, long osb, int ldo) {
  constexpr int NT = WR * WC * 64;
  constexpr int FM = BM / WR / 16, FN = BN / WC / 16;
  static_assert((BM * 8) % NT == 0 && (BN * 8) % NT == 0, "staging div");
  __shared__ u16 smem[(BM + BN) * 64];
  u16* lA = smem;
  u16* lB = smem + BM * 64;

  int bx = blockIdx.x, by = blockIdx.y;
  if constexpr (SWZ) {
    const int nwg = gridDim.x * gridDim.y;
    const int id = by * gridDim.x + bx;
    const int id2 = (id & 7) * (nwg >> 3) + (id >> 3);
    bx = id2 % gridDim.x;
    by = id2 / gridDim.x;
  }

  const int tid = threadIdx.x;
  const int lane = tid & 63;
  const int wv = tid >> 6;
  const int wr = wv / WC, wc = wv % WC;
  const int fr = lane & 15, fq = lane >> 4;
  const int bz = blockIdx.z;
  const int bzb  = (EPI == 4) ? (bz >> 1) : bz;
  const int kbeg = (EPI == 4) ? (bz & 1) * K : 0;

  const u16* Ab = A + (long)bzb * asb + (long)(by * BM) * lda;
  const u16* Bb = Bt + (long)bzb * bsb + (long)(bx * BN) * ldb;

  f32x4 acc[FM][FN];
#pragma unroll
  for (int m = 0; m < FM; ++m)
#pragma unroll
    for (int n = 0; n < FN; ++n) acc[m][n] = (f32x4)(0.f);

  for (int k0 = kbeg; k0 < kbeg + K; k0 += 64) {
#pragma unroll
    for (int p = 0; p < BM * 8 / NT; ++p) {
      int t = p * NT + tid;
      int row = t >> 3;
      int cbl = ((t & 7) << 4) ^ ((row & 7) << 4);
      gload16(Ab + (long)row * lda + k0 + (cbl >> 1), &lA[t * 8]);
    }
#pragma unroll
    for (int p = 0; p < BN * 8 / NT; ++p) {
      int t = p * NT + tid;
      int row = t >> 3;
      int cbl = ((t & 7) << 4) ^ ((row & 7) << 4);
      gload16(Bb + (long)row * ldb + k0 + (cbl >> 1), &lB[t * 8]);
    }
    __syncthreads();
#pragma unroll
    for (int ks = 0; ks < 2; ++ks) {
      short8 af[FM], bfr[FN];
#pragma unroll
      for (int m = 0; m < FM; ++m) {
        int row = wr * (BM / WR) + m * 16 + fr;
        int cb = (ks * 64 + fq * 16) ^ ((row & 7) << 4);
        af[m] = *(const short8*)((const char*)lA + row * 128 + cb);
      }
#pragma unroll
      for (int n = 0; n < FN; ++n) {
        int row = wc * (BN / WC) + n * 16 + fr;
        int cb = (ks * 64 + fq * 16) ^ ((row & 7) << 4);
        bfr[n] = *(const short8*)((const char*)lB + row * 128 + cb);
      }
#pragma unroll
      for (int m = 0; m < FM; ++m)
#pragma unroll
        for (int n = 0; n < FN; ++n)
          acc[m][n] = __builtin_amdgcn_mfma_f32_16x16x32_bf16(af[m], bfr[n], acc[m][n], 0, 0, 0);
    }
    __syncthreads();
  }

  const int ml0 = wr * (BM / WR);
  const int nl0 = wc * (BN / WC);

  if constexpr (EPI == 3) {
    const int mg0 = by * BM + ml0;
    const int ng0 = bx * BN + nl0;
#pragma unroll
    for (int m = 0; m < FM; ++m)
#pragma unroll
      for (int n = 0; n < FN; ++n) {
        const int ng = ng0 + n * 16 + fr;
#pragma unroll
        for (int r = 0; r < 4; ++r) {
          const int mg = mg0 + m * 16 + fq * 4 + r;
          const long off = (long)bz * osb + (long)mg * ldo + ng;
          of[off] = acc[m][n][r] + bias[mg] + xres[off];
        }
      }
  } else {
    const float* rls = xres + (long)(bz >> 1) * LL + by * BM;
#pragma unroll
    for (int m = 0; m < FM; ++m)
#pragma unroll
      for (int n = 0; n < FN; ++n) {
        const int nl = nl0 + n * 16 + fr;
#pragma unroll
        for (int r = 0; r < 4; ++r) {
          const int ml = ml0 + m * 16 + fq * 4 + r;
          smem[ml * BN + (nl ^ ((ml & 7) << 3))] = f2bf(acc[m][n][r] * rls[ml]);
        }
      }
    __syncthreads();
    u16* dst0 = ((bz & 1) ? o1 : o0) + (long)(bz >> 1) * NELC +
                (long)(by * BM) * ldo + bx * BN;
    for (int i = tid * 8; i < BM * BN; i += NT * 8) {
      const int rr = i / BN, cc = i % BN;
      short8 val = *(const short8*)&smem[rr * BN + (cc ^ ((rr & 7) << 3))];
      *(short8*)(dst0 + (long)rr * ldo + cc) = val;
    }
  }
}

// ---------------------------------------------------------------------------
// K4 (G=1 fallback): rls[z][i] = 1 / sum_{j<16} spp[z][j][i]
// ---------------------------------------------------------------------------
__global__ __launch_bounds__(256) void rls_combine(const float* __restrict__ spp,
                                                   float* __restrict__ rls) {
  const int row = blockIdx.x * 256 + threadIdx.x;
  const int z = blockIdx.y;
  const float* b = spp + (long)z * 16 * LL + row;
  float s = 0.f;
#pragma unroll
  for (int j = 0; j < 16; ++j) s += b[(long)j * LL];
  rls[(long)z * LL + row] = 1.0f / s;
}

// ---------------------------------------------------------------------------
// K5: sum 4 interleaved chunk-partials [4096][2048] -> [4096][512] bf16.
// ---------------------------------------------------------------------------
__global__ __launch_bounds__(256) void reduce4(
    const u16* __restrict__ P, u16* __restrict__ o) {
  const int b = blockIdx.y;
  const long idx = (long)blockIdx.x * 256 + threadIdx.x;
  const int i = (int)(idx >> 6);
  const int c0 = ((int)idx & 63) * 8;
  const u16* Pb = P + (long)b * 4 * NELC + (long)i * 2048;
  float s[8] = {0.f, 0.f, 0.f, 0.f, 0.f, 0.f, 0.f, 0.f};
#pragma unroll
  for (int c4 = 0; c4 < 4; ++c4) {
    short8 v = *(const short8*)(Pb + c4 * 512 + c0);
#pragma unroll
    for (int j = 0; j < 8; ++j) s[j] += bf2f((u16)v[j]);
  }
  short8 r;
#pragma unroll
  for (int j = 0; j < 8; ++j) r[j] = (short)f2bf(s[j]);
  *(short8*)(o + (long)b * NELC + (long)i * 512 + c0) = r;
}

// ---------------------------------------------------------------------------
// K6 (G=1 fallback): sum two bf16 partial planes -> bf16 out plane.
// ---------------------------------------------------------------------------
__global__ __launch_bounds__(256) void reduce_pp(
    const u16* __restrict__ p0, const u16* __restrict__ p1, u16* __restrict__ o) {
  const long base = (long)blockIdx.y * NELC +
                    (long)(blockIdx.x * 256 + threadIdx.x) * 16;
#pragma unroll
  for (int h = 0; h < 2; ++h) {
    short8 a = *(const short8*)(p0 + base + h * 8);
    short8 b = *(const short8*)(p1 + base + h * 8);
    short8 r;
#pragma unroll
    for (int j = 0; j < 8; ++j)
      r[j] = (short)f2bf(bf2f((u16)a[j]) + bf2f((u16)b[j]));
    *(short8*)(o + base + h * 8) = r;
  }
}

// ---------------------------------------------------------------------------
extern "C" void kernel_launch(void* const* d_in, const int* in_sizes, int n_in,
                              void* d_out, int out_size, void* d_ws, size_t ws_size,
                              hipStream_t stream) {
  const float* x   = (const float*)d_in[0];
  const float* gnw = (const float*)d_in[1];
  const float* gnb = (const float*)d_in[2];
  const float* wq  = (const float*)d_in[3];
  const float* bq  = (const float*)d_in[4];
  const float* wk  = (const float*)d_in[5];
  const float* bk  = (const float*)d_in[6];
  const float* wv  = (const float*)d_in[7];
  const float* bv  = (const float*)d_in[8];
  const float* wo  = (const float*)d_in[9];
  const float* bo  = (const float*)d_in[10];
  float* out = (float*)d_out;

  char* ws = (char*)d_ws;
  const long NEL = NELC;
  const long SEL = (long)LL * LL;
  float* stats = (float*)ws;                               // 8 KB
  float* bqkv  = (float*)(ws + 8192);                      // 6 KB
  u16* wqkv = (u16*)(ws + 16384);                          // 1.5 MB
  u16* wob  = (u16*)(ws + 16384 + 1572864);                // 0.5 MB (ends 2113536)
  float* spp  = (float*)(ws + 2113536);                    // 512 KB (16-slice sums)
  float* rlsm = (float*)(ws + (3l << 20));                 // 16 KB (G=1 path)
  u16* hT   = (u16*)(ws + (4l << 20));                     // 32 MB; PV partials after QKV
  u16* qT   = hT + 8 * NEL;                                // 32 MB  [B][L][C]
  u16* kT   = qT + 8 * NEL;                                // 32 MB  [B][L][C]
  u16* vN   = kT + 8 * NEL;                                // 32 MB  [B][C][L]
  const size_t base = (4ul << 20) + 4ul * 8 * NEL * 2;     // 132 MB

  const int G = (ws_size >= base + 2ul * SEL * 2) ? 2 : 1;
  u16* Sbuf = (G == 2) ? (u16*)(ws + base) : hT;

  prep<<<1281, 256, 0, stream>>>(wq, wk, wv, wo, bq, bk, bv, x,
                                 wqkv, wob, bqkv, stats);
  gn_apply<<<dim3(64, 8, 8), 256, 0, stream>>>(x, gnw, gnb, stats, hT);

  // fused QKV, 8-phase 256^2: A=wqkv [1536][512], Bt=hT[b] [4096][512]
  gemm8p<0><<<dim3(16, 6, 8), 512, 0, stream>>>(
      wqkv, 512, 0, hT, 512, NEL, 512, bqkv, 1.f, qT, kT, vN,
      nullptr, 0, 0);

  // no-max softmax (numerics proven r6/r7): expS = exp2(cl * q.k)
  const float cl = (1.0f / sqrtf(512.0f)) * 1.44269504f;
  for (int g0 = 0; g0 < 8; g0 += G) {
    // expS[z] = exp2(cl * qT[g0+z] * kT[g0+z]^T), 8-phase + store-loop row sums
    gemm8p<1><<<dim3(16, 16, G), 512, 0, stream>>>(
        qT + (long)g0 * NEL, 512, NEL, kT + (long)g0 * NEL, 512, NEL, 512,
        nullptr, cl, Sbuf, nullptr, nullptr, spp, SEL, LL);
    if (G == 2) {
      // PV 8-phase split-K=4, natural raster, rls fused in epilogue:
      // A=Sbuf, Bt=vN [512][4096]; partials -> hT per-batch [4096][2048].
      gemm8p<2><<<dim3(2, 16, 8), 512, 0, stream>>>(
          Sbuf, LL, SEL, vN + (long)g0 * NEL, LL, NEL, 1024,
          nullptr, 1.f, hT, nullptr, nullptr, spp, 0, 0);
      // sum 4 chunks -> attn planes in dead qT pair slots
      reduce4<<<dim3(1024, 2), 256, 0, stream>>>(hT, qT + (long)g0 * NEL);
    } else {
      rls_combine<<<dim3(16, 1), 256, 0, stream>>>(spp, rlsm);
      gemm_bt<128, 128, 4, true, 2, 4><<<dim3(4, 32, 2), 512, 0, stream>>>(
          Sbuf, LL, SEL, vN + (long)g0 * NEL, LL, NEL, 2048,
          nullptr, 1.f, qT + (long)g0 * NEL, kT + (long)g0 * NEL, nullptr,
          nullptr, rlsm, 0, CB);
      reduce_pp<<<dim3(512, 1), 256, 0, stream>>>(
          qT + (long)g0 * NEL, kT + (long)g0 * NEL, qT + (long)g0 * NEL);
    }
  }

  // out = x + wo * attn^T + bo : attn planes live in qT; M=512, N=4096, K=512
  gemm_bt<128, 128, 3, false, 2, 2><<<dim3(32, 4, 8), 256, 0, stream>>>(
      wob, 512, 0, qT, 512, NEL, 512, bo, 1.f,
      nullptr, nullptr, nullptr, out, x, NEL, LL);

  (void)in_sizes; (void)n_in; (void)out_size; (void)ws_size;
}